// Round 11
// baseline (286.402 us; speedup 1.0000x reference)
//
#include <hip/hip_runtime.h>
#include <math.h>

#define NN 100000
#define NE 2000000
#define FIN 32
#define H 32
#define NC 40

#define NBK 196      // coarse buckets: dst>>9 (512 nodes each)
#define BSH 9
#define CAP 10880    // per-bucket capacity: mean 10240 + ~6.3 sigma
#define EPT 16
#define EPB (256 * EPT)  // 4096 edges per block

#define NPROJ 12500      // prep: proj blocks (8 nodes each)
#define NCT1 10          // layer-1 ct tiles/slab: 4 gates (8) + identity (2)
#define NCT2 12          // layer-2 ct tiles/slab: 4 gates only (h2/epilogue via LDS)
#define NWB 118          // weight blocks: 10240/256 + 18432/256 + 1536/256 = 40+72+6

typedef _Float16 half_t;
typedef __attribute__((ext_vector_type(8))) _Float16 half8;
typedef __attribute__((ext_vector_type(4))) float f32x4;
typedef long long ll2 __attribute__((ext_vector_type(2)));

__device__ __forceinline__ float sigm_(float x) {
    return 1.0f / (1.0f + __expf(-x));
}
__device__ __forceinline__ float tanh_(float x) {
    x = fminf(fmaxf(x, -20.0f), 20.0f);
    float e = __expf(2.0f * x);
    return (e - 1.0f) / (e + 1.0f);
}

// ---------- shared edge-run aggregation body (explicit [e,e1) range) ----------
// Round-11: round-9 proven loop (2-way split). Callers pass degree-SORTED nodes
// (perm) so a wave's 16 groups have near-equal run lengths: divergence inflation
// max/mean drops ~1.65x -> ~1.05x. 16B half8 gathers, NT evs loads.
__device__ __forceinline__ void agg_run(int e, int e1, int q,
                                        const int2* __restrict__ evs,
                                        const half_t* __restrict__ src,
                                        float* acc) {
    const half8* s8 = (const half8*)src + q;       // 16B column chunk; row stride 4 half8
    const long long* ev8 = (const long long*)evs;  // packed (src, w)
    if ((e & 1) && e < e1) {  // head: align to 16B for pair loads
        long long r = __builtin_nontemporal_load(ev8 + e);
        float w = __int_as_float((int)(r >> 32));
        half8 hv = s8[(size_t)(r & 0x1FFFF) * 4];
#pragma unroll
        for (int t = 0; t < 8; ++t) acc[t] += w * (float)hv[t];
        ++e;
    }
    int nfull = (e1 - e) >> 3;
    if (nfull > 0) {
        ll2 p0 = __builtin_nontemporal_load((const ll2*)(ev8 + e));
        ll2 p1 = __builtin_nontemporal_load((const ll2*)(ev8 + e + 2));
        ll2 p2 = __builtin_nontemporal_load((const ll2*)(ev8 + e + 4));
        ll2 p3 = __builtin_nontemporal_load((const ll2*)(ev8 + e + 6));
        for (int it = 1; it < nfull; ++it) {
            int en = e + it * 8;
            ll2 q0 = __builtin_nontemporal_load((const ll2*)(ev8 + en));
            ll2 q1 = __builtin_nontemporal_load((const ll2*)(ev8 + en + 2));
            ll2 q2 = __builtin_nontemporal_load((const ll2*)(ev8 + en + 4));
            ll2 q3 = __builtin_nontemporal_load((const ll2*)(ev8 + en + 6));
            half8 h0 = s8[(size_t)(p0[0] & 0x1FFFF) * 4];
            half8 h1 = s8[(size_t)(p0[1] & 0x1FFFF) * 4];
            half8 h2 = s8[(size_t)(p1[0] & 0x1FFFF) * 4];
            half8 h3 = s8[(size_t)(p1[1] & 0x1FFFF) * 4];
            half8 h4 = s8[(size_t)(p2[0] & 0x1FFFF) * 4];
            half8 h5 = s8[(size_t)(p2[1] & 0x1FFFF) * 4];
            half8 h6 = s8[(size_t)(p3[0] & 0x1FFFF) * 4];
            half8 h7 = s8[(size_t)(p3[1] & 0x1FFFF) * 4];
            float w0 = __int_as_float((int)(p0[0] >> 32));
            float w1 = __int_as_float((int)(p0[1] >> 32));
            float w2 = __int_as_float((int)(p1[0] >> 32));
            float w3 = __int_as_float((int)(p1[1] >> 32));
            float w4 = __int_as_float((int)(p2[0] >> 32));
            float w5 = __int_as_float((int)(p2[1] >> 32));
            float w6 = __int_as_float((int)(p3[0] >> 32));
            float w7 = __int_as_float((int)(p3[1] >> 32));
#pragma unroll
            for (int t = 0; t < 8; ++t) {
                acc[t] += w0 * (float)h0[t];
                acc[t] += w1 * (float)h1[t];
                acc[t] += w2 * (float)h2[t];
                acc[t] += w3 * (float)h3[t];
                acc[t] += w4 * (float)h4[t];
                acc[t] += w5 * (float)h5[t];
                acc[t] += w6 * (float)h6[t];
                acc[t] += w7 * (float)h7[t];
            }
            p0 = q0;
            p1 = q1;
            p2 = q2;
            p3 = q3;
        }
        {  // drain last in-flight records
            half8 h0 = s8[(size_t)(p0[0] & 0x1FFFF) * 4];
            half8 h1 = s8[(size_t)(p0[1] & 0x1FFFF) * 4];
            half8 h2 = s8[(size_t)(p1[0] & 0x1FFFF) * 4];
            half8 h3 = s8[(size_t)(p1[1] & 0x1FFFF) * 4];
            half8 h4 = s8[(size_t)(p2[0] & 0x1FFFF) * 4];
            half8 h5 = s8[(size_t)(p2[1] & 0x1FFFF) * 4];
            half8 h6 = s8[(size_t)(p3[0] & 0x1FFFF) * 4];
            half8 h7 = s8[(size_t)(p3[1] & 0x1FFFF) * 4];
            float w0 = __int_as_float((int)(p0[0] >> 32));
            float w1 = __int_as_float((int)(p0[1] >> 32));
            float w2 = __int_as_float((int)(p1[0] >> 32));
            float w3 = __int_as_float((int)(p1[1] >> 32));
            float w4 = __int_as_float((int)(p2[0] >> 32));
            float w5 = __int_as_float((int)(p2[1] >> 32));
            float w6 = __int_as_float((int)(p3[0] >> 32));
            float w7 = __int_as_float((int)(p3[1] >> 32));
#pragma unroll
            for (int t = 0; t < 8; ++t) {
                acc[t] += w0 * (float)h0[t];
                acc[t] += w1 * (float)h1[t];
                acc[t] += w2 * (float)h2[t];
                acc[t] += w3 * (float)h3[t];
                acc[t] += w4 * (float)h4[t];
                acc[t] += w5 * (float)h5[t];
                acc[t] += w6 * (float)h6[t];
                acc[t] += w7 * (float)h7[t];
            }
        }
        e += nfull * 8;
    }
    if (e + 4 <= e1) {
        ll2 p0 = __builtin_nontemporal_load((const ll2*)(ev8 + e));
        ll2 p1 = __builtin_nontemporal_load((const ll2*)(ev8 + e + 2));
        half8 h0 = s8[(size_t)(p0[0] & 0x1FFFF) * 4];
        half8 h1 = s8[(size_t)(p0[1] & 0x1FFFF) * 4];
        half8 h2 = s8[(size_t)(p1[0] & 0x1FFFF) * 4];
        half8 h3 = s8[(size_t)(p1[1] & 0x1FFFF) * 4];
        float w0 = __int_as_float((int)(p0[0] >> 32));
        float w1 = __int_as_float((int)(p0[1] >> 32));
        float w2 = __int_as_float((int)(p1[0] >> 32));
        float w3 = __int_as_float((int)(p1[1] >> 32));
#pragma unroll
        for (int t = 0; t < 8; ++t) {
            acc[t] += w0 * (float)h0[t];
            acc[t] += w1 * (float)h1[t];
            acc[t] += w2 * (float)h2[t];
            acc[t] += w3 * (float)h3[t];
        }
        e += 4;
    }
    if (e + 2 <= e1) {
        ll2 p0 = __builtin_nontemporal_load((const ll2*)(ev8 + e));
        half8 h0 = s8[(size_t)(p0[0] & 0x1FFFF) * 4];
        half8 h1 = s8[(size_t)(p0[1] & 0x1FFFF) * 4];
        float w0 = __int_as_float((int)(p0[0] >> 32));
        float w1 = __int_as_float((int)(p0[1] >> 32));
#pragma unroll
        for (int t = 0; t < 8; ++t) {
            acc[t] += w0 * (float)h0[t];
            acc[t] += w1 * (float)h1[t];
        }
        e += 2;
    }
    if (e < e1) {  // tail single
        long long r = __builtin_nontemporal_load(ev8 + e);
        float w = __int_as_float((int)(r >> 32));
        half8 hv = s8[(size_t)(r & 0x1FFFF) * 4];
#pragma unroll
        for (int t = 0; t < 8; ++t) acc[t] += w * (float)hv[t];
    }
}

// ---------- phase A: coarse-bucket scatter with LDS staging ----------
__global__ __launch_bounds__(256) void kA_bucket(const int* __restrict__ ei,
                                                 const float* __restrict__ ew,
                                                 int* __restrict__ gcur,
                                                 long long* __restrict__ rec) {
    __shared__ long long recs[EPB];   // 32 KB bucket-sorted records
    __shared__ int gdst[EPB];         // 16 KB absolute global slot per record
    __shared__ int cnt[NBK], base[NBK], sofs[NBK];
    __shared__ int ssc[256];
    int tid = threadIdx.x;
    for (int i = tid; i < NBK; i += 256) cnt[i] = 0;
    __syncthreads();
    int e0 = blockIdx.x * EPB;
    int dcache[EPT];
#pragma unroll
    for (int i = 0; i < EPT; ++i) {
        int e = e0 + i * 256 + tid;
        dcache[i] = (e < NE) ? ei[NE + e] : -1;
        if (e < NE) atomicAdd(&cnt[dcache[i] >> BSH], 1);
    }
    __syncthreads();
    int cv = (tid < NBK) ? cnt[tid] : 0;
    ssc[tid] = cv;
    __syncthreads();
    for (int off = 1; off < 256; off <<= 1) {
        int v = (tid >= off) ? ssc[tid - off] : 0;
        __syncthreads();
        ssc[tid] += v;
        __syncthreads();
    }
    if (tid < NBK) {
        sofs[tid] = ssc[tid] - cv;
        base[tid] = atomicAdd(&gcur[tid], cv);  // one global atomic per (block,bucket)
        cnt[tid] = 0;                           // reuse as rank cursor
    }
    __syncthreads();
#pragma unroll
    for (int i = 0; i < EPT; ++i) {
        int e = e0 + i * 256 + tid;
        if (e < NE) {
            int d = dcache[i], s = ei[e];
            int b = d >> BSH;
            int r = atomicAdd(&cnt[b], 1);
            int slot = sofs[b] + r;
            int pos = base[b] + r;
            int lo = s | ((d & 511) << 17);
            recs[slot] = (long long)(unsigned)lo |
                         ((long long)__float_as_int(ew[e]) << 32);
            gdst[slot] = (pos < CAP) ? (b * CAP + pos) : -1;  // overflow guard
        }
    }
    __syncthreads();
    int nrec = min(EPB, NE - e0);
    for (int i = tid; i < nrec; i += 256) {
        int gd = gdst[i];
        if (gd >= 0) rec[gd] = recs[i];
    }
}

// ---------- phase B: counting sort by (dst_local, src_slice) + degree-sorted perm ----------
// dst-major slice-minor: node's edges contiguous; slice-ordered within node keeps
// the grid's gathers in ~2 adjacent ~2.1 MB table slices (XCD-L2 resident).
// NEW (round-11): bucket-local degree sort -> perm so k_l1/k_l2 waves group
// nodes of near-equal degree (kills the max-over-16-groups divergence tax).
__global__ __launch_bounds__(256) void kB_sort(const int* __restrict__ gcur,
                                               const int2* __restrict__ rec,
                                               int2* __restrict__ evs,
                                               int* __restrict__ ofs,
                                               int* __restrict__ ocn,
                                               int* __restrict__ perm) {
    __shared__ int hist[2048], lofs[2048], ssc[256];
    __shared__ int dh[64], dcur[64];
    int tid = threadIdx.x, b = blockIdx.x;
    int nb0 = b << BSH;
    int nnodes = min(512, NN - nb0);
    int cntb = min(gcur[b], CAP);
    for (int i = tid; i < 2048; i += 256) hist[i] = 0;
    if (tid < 64) {
        dh[tid] = 0;
        dcur[tid] = 0;
    }
    __syncthreads();
    const int2* rb = rec + (size_t)b * CAP;
    for (int i = tid; i < cntb; i += 256) {
        int rx = rb[i].x;
        int bin = (((rx >> 17) & 511) << 2) | ((rx & 0x1FFFF) >> 15);
        atomicAdd(&hist[bin], 1);
    }
    __syncthreads();
    int base = tid * 8, ls = 0, lh[8];
#pragma unroll
    for (int j = 0; j < 8; ++j) {
        lh[j] = hist[base + j];
        ls += lh[j];
    }
    ssc[tid] = ls;
    __syncthreads();
    for (int off = 1; off < 256; off <<= 1) {
        int v = (tid >= off) ? ssc[tid - off] : 0;
        __syncthreads();
        ssc[tid] += v;
        __syncthreads();
    }
    int ex = ssc[tid] - ls;
#pragma unroll
    for (int j = 0; j < 8; ++j) {
        lofs[base + j] = ex;
        ex += lh[j];
    }
    __syncthreads();
    for (int l = tid; l < nnodes; l += 256) {  // per-node CSR meta + degree histogram
        int c = hist[4 * l] + hist[4 * l + 1] + hist[4 * l + 2] + hist[4 * l + 3];
        ofs[nb0 + l] = b * CAP + lofs[4 * l];
        ocn[nb0 + l] = c;
        atomicAdd(&dh[min(c, 63)], 1);
    }
    __syncthreads();
    if (tid == 0) {  // exclusive scan of 64 degree bins (cheap serial)
        int run = 0;
#pragma unroll
        for (int d = 0; d < 64; ++d) {
            int v = dh[d];
            dh[d] = run;
            run += v;
        }
    }
    __syncthreads();
    for (int l = tid; l < nnodes; l += 256) {  // emit degree-sorted perm
        int c = hist[4 * l] + hist[4 * l + 1] + hist[4 * l + 2] + hist[4 * l + 3];
        int d = min(c, 63);
        int r = atomicAdd(&dcur[d], 1);
        perm[nb0 + dh[d] + r] = nb0 + l;
    }
    __syncthreads();
    for (int i = tid; i < 2048; i += 256) hist[i] = 0;
    __syncthreads();
    int2* eb = evs + (size_t)b * CAP;
    for (int i = tid; i < cntb; i += 256) {
        int2 r = rb[i];
        int bin = (((r.x >> 17) & 511) << 2) | ((r.x & 0x1FFFF) >> 15);
        int rk = atomicAdd(&hist[bin], 1);
        eb[lofs[bin] + rk] = make_int2(r.x & 0x1FFFF, r.y);
    }
}

// ---------- prep: gcur zero + weight tables + x@W1p -> Hd, one dispatch ----------
__global__ __launch_bounds__(256) void k_prep(const float* __restrict__ x,
                                              const float* __restrict__ W1p,
                                              const float* __restrict__ W1m,
                                              const float* __restrict__ wih1,
                                              const float* __restrict__ whh1,
                                              const float* __restrict__ W2p,
                                              const float* __restrict__ W2m,
                                              const float* __restrict__ wih2,
                                              const float* __restrict__ whh2,
                                              half_t* __restrict__ Hd,
                                              half_t* __restrict__ W1sw,
                                              half_t* __restrict__ W2sw,
                                              half_t* __restrict__ W2pf,
                                              int* __restrict__ gcur) {
    __shared__ float sWp[FIN * H];   // proj weights
    __shared__ float sx[8][FIN];     // proj inputs
    __shared__ float P2l[32 * NC];   // weight blocks: P2 = W2p @ W2m
    int b = blockIdx.x, tid = threadIdx.x;
    if (b < NPROJ) {  // ---- h1 = x @ W1p (8 nodes/block) -> dense Hd ----
        for (int i = tid; i < FIN * H; i += 256) sWp[i] = W1p[i];
        int nb = b * 8;
        int nl = tid >> 5, j = tid & 31;
        int n = nb + nl;
        if (n < NN) sx[nl][j] = x[(size_t)n * FIN + j];
        __syncthreads();
        float acc = 0.f;
#pragma unroll
        for (int k = 0; k < FIN; ++k) acc += sx[nl][k] * sWp[k * H + j];
        if (n < NN) Hd[(size_t)n * 32 + j] = (half_t)acc;
        return;
    }
    int wb = b - NPROJ;
    if (wb == 0 && tid < NBK) gcur[tid] = 0;  // replaces hipMemsetAsync dispatch
    if (wb < 40) {  // ---- layer-1 table: 2 slabs x 10 ct ----
        int i = wb * 256 + tid;  // < 10240
        int j = i & 7, lane = (i >> 3) & 63;
        int rest = i >> 9;  // 0..19
        int ct = rest % NCT1, s = rest / NCT1;
        int k = s * 32 + (lane >> 4) * 8 + j;
        int col = ct * 16 + (lane & 15);
        int g = col >> 5, jj = col & 31;  // g: 0=r 1=z 2=i_n 3=h_n 4=identity
        float v = 0.f;
        if (g <= 2) {
            if (k < 32) {  // input side (agg): fold W1m @ wih1^T
                float acc = 0.f;
#pragma unroll
                for (int t = 0; t < H; ++t) acc += W1m[k * H + t] * wih1[(g * H + jj) * H + t];
                v = acc;
            } else if (g < 2) {  // r,z hidden side
                v = whh1[(g * H + jj) * H + (k - 32)];
            }                     // g==2 (i_n), k>=32 -> 0
        } else if (g == 3) {      // h_n: hidden side only
            if (k >= 32) v = whh1[(2 * H + jj) * H + (k - 32)];
        } else {                  // identity: pass h1 (k=32..63) to C cols 128..159
            if (k >= 32 && (k - 32) == jj) v = 1.f;
        }
        W1sw[i] = (half_t)v;
    } else if (wb < 112) {  // ---- layer-2 table: 3 slabs x 12 ct ----
        for (int e = tid; e < 32 * NC; e += 256) {  // P2[k][t] = sum_u W2p[k,u]*W2m[u,t]
            int k = e / NC, t = e % NC;
            float a = 0.f;
#pragma unroll
            for (int u = 0; u < NC; ++u) a += W2p[k * NC + u] * W2m[u * NC + t];
            P2l[e] = a;
        }
        __syncthreads();
        int i2 = (wb - 40) * 256 + tid;  // < 18432
        int j = i2 & 7, lane = (i2 >> 3) & 63;
        int rest = i2 >> 9;  // 0..35
        int ct = rest % NCT2, s = rest / NCT2;
        int k = s * 32 + (lane >> 4) * 8 + j;  // 0..95
        int col = ct * 16 + (lane & 15);       // 0..191
        int g = col / 48, jj = col % 48;       // g: 0=r 1=z 2=i_n 3=h_n
        float v = 0.f;
        if (jj < NC) {
            if (g <= 2) {
                if (k < 32) {  // input side (agg): P2 @ wih2^T
                    float acc = 0.f;
#pragma unroll
                    for (int t = 0; t < NC; ++t)
                        acc += P2l[k * NC + t] * wih2[(g * NC + jj) * NC + t];
                    v = acc;
                } else if (k < 72 && g < 2) {  // r,z hidden side
                    v = whh2[(g * NC + jj) * NC + (k - 32)];
                }
            } else {  // g==3 (h_n)
                if (k >= 32 && k < 72) v = whh2[(2 * NC + jj) * NC + (k - 32)];
            }
        }
        W2sw[i2] = (half_t)v;
    } else {  // ---- W2pf: W2p fragment-linear fp16, 1 slab x 3 ct ----
        int i3 = (wb - 112) * 256 + tid;  // < 1536
        int j = i3 & 7, lane = (i3 >> 3) & 63, ct = i3 >> 9;  // ct 0..2
        int k = (lane >> 4) * 8 + j;        // 0..31
        int col = ct * 16 + (lane & 15);    // 0..47
        W2pf[i3] = (half_t)((col < NC) ? W2p[k * NC + col] : 0.f);
    }
}

// ---------- L1 fused: degree-balanced split-run agg + MFMA GRU1 + relu ----------
// 128 threads / 16 perm-sorted nodes: 8 lanes/node = 2 x 4-lane groups. Wave 0
// combines partials (fp32) + runs MFMA/epilogue; wave 1 exits after agg.
__global__ __launch_bounds__(128, 4) void k_l1(const int* __restrict__ ofs,
                                               const int* __restrict__ ocn,
                                               const int2* __restrict__ evs,
                                               const int* __restrict__ perm,
                                               const half_t* __restrict__ Hd,
                                               const half8* __restrict__ W1sw,
                                               const float* __restrict__ bih,
                                               const float* __restrict__ bhh,
                                               half_t* __restrict__ Hh) {
    __shared__ half8 aggT[16][9];  // 144B row stride: bank-uniform b128 access
    __shared__ int sperm[16];
    int tid = threadIdx.x;
    int n0 = blockIdx.x * 16;
    if (tid < 16) sperm[tid] = perm[n0 + tid];
    half8 a1;
    if (tid < 64) a1 = ((const half8*)Hd)[(size_t)perm[n0 + (tid & 15)] * 4 + (tid >> 4)];
    {  // agg: permuted node nl, group g (half-run), col-quad q
        int nl = tid >> 3, s = tid & 7, g = s >> 2, q = s & 3;
        int n = perm[n0 + nl];
        int s0 = ofs[n], c = ocn[n];
        int c0 = (c + 1) >> 1;
        int eb = g ? (s0 + c0) : s0;
        int ee = g ? (s0 + c) : (s0 + c0);
        float acc[8] = {0.f, 0.f, 0.f, 0.f, 0.f, 0.f, 0.f, 0.f};
        agg_run(eb, ee, q, evs, Hd, acc);
        half8 o;
#pragma unroll
        for (int t = 0; t < 8; ++t) o[t] = (half_t)acc[t];
        aggT[nl][s] = o;
    }
    __syncthreads();
    if (tid >= 64) return;  // wave 1 done
    int lane = tid, m16 = lane & 15, qq = lane >> 4;
    half8 pa = aggT[m16][qq], pb = aggT[m16][4 + qq];
    half8 a0;
#pragma unroll
    for (int t = 0; t < 8; ++t) a0[t] = (half_t)((float)pa[t] + (float)pb[t]);
    f32x4 macc[NCT1];
#pragma unroll
    for (int ct = 0; ct < NCT1; ++ct) macc[ct] = (f32x4){0.f, 0.f, 0.f, 0.f};
#pragma unroll
    for (int ct = 0; ct < NCT1; ++ct) {
        macc[ct] = __builtin_amdgcn_mfma_f32_16x16x32_f16(a0, W1sw[ct * 64 + lane], macc[ct], 0, 0, 0);
        macc[ct] = __builtin_amdgcn_mfma_f32_16x16x32_f16(a1, W1sw[(NCT1 + ct) * 64 + lane], macc[ct], 0, 0, 0);
    }
#pragma unroll
    for (int ct = 0; ct < 2; ++ct) {
        int j = ct * 16 + m16;
        float br = bih[j] + bhh[j];
        float bz = bih[H + j] + bhh[H + j];
        float bi = bih[2 * H + j], bh = bhh[2 * H + j];
#pragma unroll
        for (int m = 0; m < 4; ++m) {
            int node = sperm[qq * 4 + m];  // C/D: row = quad*4 + reg, col = lane&15
            float r = sigm_(macc[ct][m] + br);
            float z = sigm_(macc[2 + ct][m] + bz);
            float ng = tanh_(macc[4 + ct][m] + bi + r * (macc[6 + ct][m] + bh));
            float hj = macc[8 + ct][m];  // identity gate: h1[node][j]
            float o = fmaxf((1.f - z) * ng + z * hj, 0.f);
            Hh[(size_t)node * 32 + j] = (half_t)o;
        }
    }
}

// ---------- L2 fused: h2-via-MFMA + degree-balanced agg + MFMA GRU2 + log_softmax ----------
__global__ __launch_bounds__(128, 4) void k_l2(const int* __restrict__ ofs,
                                               const int* __restrict__ ocn,
                                               const int2* __restrict__ evs,
                                               const int* __restrict__ perm,
                                               const half_t* __restrict__ Hh,
                                               const half8* __restrict__ W2sw,
                                               const half8* __restrict__ W2pf,
                                               const float* __restrict__ bih,
                                               const float* __restrict__ bhh,
                                               float* __restrict__ out) {
    __shared__ half8 aggT[16][9];   // 2304B, padded
    __shared__ half_t h2c[16][72];  // 2304B: h2 cols 0..39, zeros 40..71 (144B stride)
    __shared__ int sperm[16];
    int tid = threadIdx.x;
    int n0 = blockIdx.x * 16;
    if (tid < 16) sperm[tid] = perm[n0 + tid];
    if (tid < 64) {  // wave 0: h2 via MFMA (A = Hh rows of the block's 16 perm nodes)
        int lane = tid, m16 = lane & 15, qq = lane >> 4;
        half8 ah = ((const half8*)Hh)[(size_t)perm[n0 + m16] * 4 + qq];
        f32x4 hC[3];
#pragma unroll
        for (int ct = 0; ct < 3; ++ct) hC[ct] = (f32x4){0.f, 0.f, 0.f, 0.f};
#pragma unroll
        for (int ct = 0; ct < 3; ++ct)
            hC[ct] = __builtin_amdgcn_mfma_f32_16x16x32_f16(ah, W2pf[ct * 64 + lane], hC[ct], 0, 0, 0);
        // C-layout park at LOCAL row indices (cols 40..47 are 0 from W2pf zero-pad)
#pragma unroll
        for (int ct = 0; ct < 3; ++ct)
#pragma unroll
            for (int m = 0; m < 4; ++m)
                h2c[qq * 4 + m][ct * 16 + m16] = (half_t)hC[ct][m];
    } else {  // wave 1: zero h2c cols 48..71
        int t2 = tid - 64;
        for (int i5 = t2; i5 < 16 * 24; i5 += 64)
            h2c[i5 / 24][48 + i5 % 24] = (half_t)0.f;
    }
    {  // agg (both waves): permuted node nl, group g, col-quad q
        int nl = tid >> 3, s = tid & 7, g = s >> 2, q = s & 3;
        int n = perm[n0 + nl];
        int s0 = ofs[n], c = ocn[n];
        int c0 = (c + 1) >> 1;
        int eb = g ? (s0 + c0) : s0;
        int ee = g ? (s0 + c) : (s0 + c0);
        float acc[8] = {0.f, 0.f, 0.f, 0.f, 0.f, 0.f, 0.f, 0.f};
        agg_run(eb, ee, q, evs, Hh, acc);
        half8 o;
#pragma unroll
        for (int t = 0; t < 8; ++t) o[t] = (half_t)acc[t];
        aggT[nl][s] = o;
    }
    __syncthreads();
    if (tid >= 64) return;  // wave 1 done
    int lane = tid, m16 = lane & 15, qq = lane >> 4;
    half8 pa = aggT[m16][qq], pb = aggT[m16][4 + qq];
    half8 a0;
#pragma unroll
    for (int t = 0; t < 8; ++t) a0[t] = (half_t)((float)pa[t] + (float)pb[t]);
    half8 a1 = *(const half8*)&h2c[m16][qq * 8];       // h2 cols 0..31
    half8 a2 = *(const half8*)&h2c[m16][32 + qq * 8];  // cols 32..63 (40+ = 0)
    f32x4 macc[NCT2];
#pragma unroll
    for (int ct = 0; ct < NCT2; ++ct) macc[ct] = (f32x4){0.f, 0.f, 0.f, 0.f};
#pragma unroll
    for (int ct = 0; ct < NCT2; ++ct) {
        macc[ct] = __builtin_amdgcn_mfma_f32_16x16x32_f16(a0, W2sw[ct * 64 + lane], macc[ct], 0, 0, 0);
        macc[ct] = __builtin_amdgcn_mfma_f32_16x16x32_f16(a1, W2sw[(NCT2 + ct) * 64 + lane], macc[ct], 0, 0, 0);
        macc[ct] = __builtin_amdgcn_mfma_f32_16x16x32_f16(a2, W2sw[(2 * NCT2 + ct) * 64 + lane], macc[ct], 0, 0, 0);
    }
    float v[3][4];
#pragma unroll
    for (int ct = 0; ct < 3; ++ct) {
        int j = ct * 16 + m16;
        int jc = (j < NC) ? j : (NC - 1);  // clamp (lanes with j>=40 produce unused values)
        float br = bih[jc] + bhh[jc];
        float bz = bih[NC + jc] + bhh[NC + jc];
        float bi = bih[2 * NC + jc], bh = bhh[2 * NC + jc];
#pragma unroll
        for (int m = 0; m < 4; ++m) {
            float r = sigm_(macc[ct][m] + br);
            float z = sigm_(macc[3 + ct][m] + bz);
            float ng = tanh_(macc[6 + ct][m] + bi + r * (macc[9 + ct][m] + bh));
            float hj = (float)h2c[qq * 4 + m][jc];
            v[ct][m] = (1.f - z) * ng + z * hj;
        }
    }
    bool v2ok = (m16 < 8);  // ct=2 covers j=32..39 only for m16<8
#pragma unroll
    for (int m = 0; m < 4; ++m) {
        float mx = fmaxf(v[0][m], v[1][m]);
        if (v2ok) mx = fmaxf(mx, v[2][m]);
#pragma unroll
        for (int d = 1; d < 16; d <<= 1) mx = fmaxf(mx, __shfl_xor(mx, d));
        float se = __expf(v[0][m] - mx) + __expf(v[1][m] - mx) +
                   (v2ok ? __expf(v[2][m] - mx) : 0.f);
#pragma unroll
        for (int d = 1; d < 16; d <<= 1) se += __shfl_xor(se, d);
        float ls = mx + __logf(se);
        int node = sperm[qq * 4 + m];
        out[(size_t)node * NC + m16] = v[0][m] - ls;
        out[(size_t)node * NC + 16 + m16] = v[1][m] - ls;
        if (v2ok) out[(size_t)node * NC + 32 + m16] = v[2][m] - ls;
    }
}

extern "C" void kernel_launch(void* const* d_in, const int* in_sizes, int n_in,
                              void* d_out, int out_size, void* d_ws, size_t ws_size,
                              hipStream_t stream) {
    const float* x = (const float*)d_in[0];
    const int* ei = (const int*)d_in[1];
    const float* ew = (const float*)d_in[2];
    const float* W1p = (const float*)d_in[3];
    const float* W1m = (const float*)d_in[4];
    const float* g1wih = (const float*)d_in[5];
    const float* g1whh = (const float*)d_in[6];
    const float* g1bih = (const float*)d_in[7];
    const float* g1bhh = (const float*)d_in[8];
    const float* W2p = (const float*)d_in[9];
    const float* W2m = (const float*)d_in[10];
    const float* g2wih = (const float*)d_in[11];
    const float* g2whh = (const float*)d_in[12];
    const float* g2bih = (const float*)d_in[13];
    const float* g2bhh = (const float*)d_in[14];
    float* ws = (float*)d_ws;

    // workspace layout (float indices), ~48.2 MB:
    //  rec  [0, 4264960)         kA bucket scratch
    //  evs  [4264960, 8529920)   sorted records
    //  Hd   [8529920, 10130176)  dense [NN][32] fp16 h1 table
    //  Hh   [10130176, 11730432) dense [NN][32] fp16 hrelu table
    //  ofs  [11730432, 11830432) int[NN]
    //  ocn  [11830432, 11930432) int[NN]
    //  gcur [11930432, 11930688)
    //  perm [11930688, 12030688) int[NN] degree-sorted node order
    //  W1sw (10240 h) / W2sw (18432 h) / W2pf (1536 h) tail
    long long* rec = (long long*)ws;
    int2* evs = (int2*)(ws + 4264960);
    half_t* Hd = (half_t*)(ws + 8529920);
    half_t* Hh = (half_t*)(ws + 10130176);
    int* ofs = (int*)(ws + 11730432);
    int* ocn = (int*)(ws + 11830432);
    int* gcur = (int*)(ws + 11930432);
    int* perm = (int*)(ws + 11930688);
    half_t* W1sw = (half_t*)(ws + 12030688);
    half_t* W2sw = W1sw + 10240;
    half_t* W2pf = W2sw + 18432;
    float* out = (float*)d_out;

    // 5 dispatches total
    k_prep<<<NPROJ + NWB, 256, 0, stream>>>(x, W1p, W1m, g1wih, g1whh,
                                            W2p, W2m, g2wih, g2whh,
                                            Hd, W1sw, W2sw, W2pf, gcur);
    kA_bucket<<<(NE + EPB - 1) / EPB, 256, 0, stream>>>(ei, ew, gcur, rec);
    kB_sort<<<NBK, 256, 0, stream>>>(gcur, (const int2*)rec, evs, ofs, ocn, perm);
    k_l1<<<NN / 16, 128, 0, stream>>>(ofs, ocn, evs, perm, Hd, (const half8*)W1sw,
                                      g1bih, g1bhh, Hh);
    k_l2<<<NN / 16, 128, 0, stream>>>(ofs, ocn, evs, perm, Hh, (const half8*)W2sw,
                                      (const half8*)W2pf, g2bih, g2bhh, out);
}

// Round 13
// 257.816 us; speedup vs baseline: 1.1109x; 1.1109x over previous
//
#include <hip/hip_runtime.h>
#include <math.h>

#define NN 100000
#define NE 2000000
#define FIN 32
#define H 32
#define NC 40

#define NBK 196      // coarse buckets: dst>>9 (512 nodes each)
#define BSH 9
#define CAP 10880    // per-bucket capacity: mean 10240 + ~6.3 sigma
#define EPT 16
#define EPB (256 * EPT)  // 4096 edges per block

#define NPROJ 12500      // prep: proj blocks (8 nodes each)
#define NCT1 10          // layer-1 ct tiles/slab: 4 gates (8) + identity (2)
#define NCT2 12          // layer-2 ct tiles/slab: 4 gates only (h2/epilogue via LDS)
#define NWB 118          // weight blocks: 10240/256 + 18432/256 + 1536/256 = 40+72+6

typedef _Float16 half_t;
typedef __attribute__((ext_vector_type(8))) _Float16 half8;
typedef __attribute__((ext_vector_type(4))) float f32x4;
typedef long long ll2 __attribute__((ext_vector_type(2)));

__device__ __forceinline__ float sigm_(float x) {
    return 1.0f / (1.0f + __expf(-x));
}
__device__ __forceinline__ float tanh_(float x) {
    x = fminf(fmaxf(x, -20.0f), 20.0f);
    float e = __expf(2.0f * x);
    return (e - 1.0f) / (e + 1.0f);
}

// ---------- shared edge-run aggregation body (explicit [e,e1) range) ----------
// Round-13 resubmit of round-9 best (258.8 us measured; round-12 bench was an
// infra failure). Ledger: traffic floor reached (FETCH ~80 MB structural),
// conflicts fixed, SW pipelining null, wave supply x2/x4 null-to-negative,
// divergence fix locality-negative -> agg at L2 random-request serialization
// floor for this structure.
__device__ __forceinline__ void agg_run(int e, int e1, int q,
                                        const int2* __restrict__ evs,
                                        const half_t* __restrict__ src,
                                        float* acc) {
    const half8* s8 = (const half8*)src + q;       // 16B column chunk; row stride 4 half8
    const long long* ev8 = (const long long*)evs;  // packed (src, w)
    if ((e & 1) && e < e1) {  // head: align to 16B for pair loads
        long long r = __builtin_nontemporal_load(ev8 + e);
        float w = __int_as_float((int)(r >> 32));
        half8 hv = s8[(size_t)(r & 0x1FFFF) * 4];
#pragma unroll
        for (int t = 0; t < 8; ++t) acc[t] += w * (float)hv[t];
        ++e;
    }
    int nfull = (e1 - e) >> 3;
    if (nfull > 0) {
        ll2 p0 = __builtin_nontemporal_load((const ll2*)(ev8 + e));
        ll2 p1 = __builtin_nontemporal_load((const ll2*)(ev8 + e + 2));
        ll2 p2 = __builtin_nontemporal_load((const ll2*)(ev8 + e + 4));
        ll2 p3 = __builtin_nontemporal_load((const ll2*)(ev8 + e + 6));
        for (int it = 1; it < nfull; ++it) {
            int en = e + it * 8;
            ll2 q0 = __builtin_nontemporal_load((const ll2*)(ev8 + en));
            ll2 q1 = __builtin_nontemporal_load((const ll2*)(ev8 + en + 2));
            ll2 q2 = __builtin_nontemporal_load((const ll2*)(ev8 + en + 4));
            ll2 q3 = __builtin_nontemporal_load((const ll2*)(ev8 + en + 6));
            half8 h0 = s8[(size_t)(p0[0] & 0x1FFFF) * 4];
            half8 h1 = s8[(size_t)(p0[1] & 0x1FFFF) * 4];
            half8 h2 = s8[(size_t)(p1[0] & 0x1FFFF) * 4];
            half8 h3 = s8[(size_t)(p1[1] & 0x1FFFF) * 4];
            half8 h4 = s8[(size_t)(p2[0] & 0x1FFFF) * 4];
            half8 h5 = s8[(size_t)(p2[1] & 0x1FFFF) * 4];
            half8 h6 = s8[(size_t)(p3[0] & 0x1FFFF) * 4];
            half8 h7 = s8[(size_t)(p3[1] & 0x1FFFF) * 4];
            float w0 = __int_as_float((int)(p0[0] >> 32));
            float w1 = __int_as_float((int)(p0[1] >> 32));
            float w2 = __int_as_float((int)(p1[0] >> 32));
            float w3 = __int_as_float((int)(p1[1] >> 32));
            float w4 = __int_as_float((int)(p2[0] >> 32));
            float w5 = __int_as_float((int)(p2[1] >> 32));
            float w6 = __int_as_float((int)(p3[0] >> 32));
            float w7 = __int_as_float((int)(p3[1] >> 32));
#pragma unroll
            for (int t = 0; t < 8; ++t) {
                acc[t] += w0 * (float)h0[t];
                acc[t] += w1 * (float)h1[t];
                acc[t] += w2 * (float)h2[t];
                acc[t] += w3 * (float)h3[t];
                acc[t] += w4 * (float)h4[t];
                acc[t] += w5 * (float)h5[t];
                acc[t] += w6 * (float)h6[t];
                acc[t] += w7 * (float)h7[t];
            }
            p0 = q0;
            p1 = q1;
            p2 = q2;
            p3 = q3;
        }
        {  // drain last in-flight records
            half8 h0 = s8[(size_t)(p0[0] & 0x1FFFF) * 4];
            half8 h1 = s8[(size_t)(p0[1] & 0x1FFFF) * 4];
            half8 h2 = s8[(size_t)(p1[0] & 0x1FFFF) * 4];
            half8 h3 = s8[(size_t)(p1[1] & 0x1FFFF) * 4];
            half8 h4 = s8[(size_t)(p2[0] & 0x1FFFF) * 4];
            half8 h5 = s8[(size_t)(p2[1] & 0x1FFFF) * 4];
            half8 h6 = s8[(size_t)(p3[0] & 0x1FFFF) * 4];
            half8 h7 = s8[(size_t)(p3[1] & 0x1FFFF) * 4];
            float w0 = __int_as_float((int)(p0[0] >> 32));
            float w1 = __int_as_float((int)(p0[1] >> 32));
            float w2 = __int_as_float((int)(p1[0] >> 32));
            float w3 = __int_as_float((int)(p1[1] >> 32));
            float w4 = __int_as_float((int)(p2[0] >> 32));
            float w5 = __int_as_float((int)(p2[1] >> 32));
            float w6 = __int_as_float((int)(p3[0] >> 32));
            float w7 = __int_as_float((int)(p3[1] >> 32));
#pragma unroll
            for (int t = 0; t < 8; ++t) {
                acc[t] += w0 * (float)h0[t];
                acc[t] += w1 * (float)h1[t];
                acc[t] += w2 * (float)h2[t];
                acc[t] += w3 * (float)h3[t];
                acc[t] += w4 * (float)h4[t];
                acc[t] += w5 * (float)h5[t];
                acc[t] += w6 * (float)h6[t];
                acc[t] += w7 * (float)h7[t];
            }
        }
        e += nfull * 8;
    }
    if (e + 4 <= e1) {
        ll2 p0 = __builtin_nontemporal_load((const ll2*)(ev8 + e));
        ll2 p1 = __builtin_nontemporal_load((const ll2*)(ev8 + e + 2));
        half8 h0 = s8[(size_t)(p0[0] & 0x1FFFF) * 4];
        half8 h1 = s8[(size_t)(p0[1] & 0x1FFFF) * 4];
        half8 h2 = s8[(size_t)(p1[0] & 0x1FFFF) * 4];
        half8 h3 = s8[(size_t)(p1[1] & 0x1FFFF) * 4];
        float w0 = __int_as_float((int)(p0[0] >> 32));
        float w1 = __int_as_float((int)(p0[1] >> 32));
        float w2 = __int_as_float((int)(p1[0] >> 32));
        float w3 = __int_as_float((int)(p1[1] >> 32));
#pragma unroll
        for (int t = 0; t < 8; ++t) {
            acc[t] += w0 * (float)h0[t];
            acc[t] += w1 * (float)h1[t];
            acc[t] += w2 * (float)h2[t];
            acc[t] += w3 * (float)h3[t];
        }
        e += 4;
    }
    if (e + 2 <= e1) {
        ll2 p0 = __builtin_nontemporal_load((const ll2*)(ev8 + e));
        half8 h0 = s8[(size_t)(p0[0] & 0x1FFFF) * 4];
        half8 h1 = s8[(size_t)(p0[1] & 0x1FFFF) * 4];
        float w0 = __int_as_float((int)(p0[0] >> 32));
        float w1 = __int_as_float((int)(p0[1] >> 32));
#pragma unroll
        for (int t = 0; t < 8; ++t) {
            acc[t] += w0 * (float)h0[t];
            acc[t] += w1 * (float)h1[t];
        }
        e += 2;
    }
    if (e < e1) {  // tail single
        long long r = __builtin_nontemporal_load(ev8 + e);
        float w = __int_as_float((int)(r >> 32));
        half8 hv = s8[(size_t)(r & 0x1FFFF) * 4];
#pragma unroll
        for (int t = 0; t < 8; ++t) acc[t] += w * (float)hv[t];
    }
}

// ---------- phase A: coarse-bucket scatter with LDS staging ----------
__global__ __launch_bounds__(256) void kA_bucket(const int* __restrict__ ei,
                                                 const float* __restrict__ ew,
                                                 int* __restrict__ gcur,
                                                 long long* __restrict__ rec) {
    __shared__ long long recs[EPB];   // 32 KB bucket-sorted records
    __shared__ int gdst[EPB];         // 16 KB absolute global slot per record
    __shared__ int cnt[NBK], base[NBK], sofs[NBK];
    __shared__ int ssc[256];
    int tid = threadIdx.x;
    for (int i = tid; i < NBK; i += 256) cnt[i] = 0;
    __syncthreads();
    int e0 = blockIdx.x * EPB;
    int dcache[EPT];
#pragma unroll
    for (int i = 0; i < EPT; ++i) {
        int e = e0 + i * 256 + tid;
        dcache[i] = (e < NE) ? ei[NE + e] : -1;
        if (e < NE) atomicAdd(&cnt[dcache[i] >> BSH], 1);
    }
    __syncthreads();
    int cv = (tid < NBK) ? cnt[tid] : 0;
    ssc[tid] = cv;
    __syncthreads();
    for (int off = 1; off < 256; off <<= 1) {
        int v = (tid >= off) ? ssc[tid - off] : 0;
        __syncthreads();
        ssc[tid] += v;
        __syncthreads();
    }
    if (tid < NBK) {
        sofs[tid] = ssc[tid] - cv;
        base[tid] = atomicAdd(&gcur[tid], cv);  // one global atomic per (block,bucket)
        cnt[tid] = 0;                           // reuse as rank cursor
    }
    __syncthreads();
#pragma unroll
    for (int i = 0; i < EPT; ++i) {
        int e = e0 + i * 256 + tid;
        if (e < NE) {
            int d = dcache[i], s = ei[e];
            int b = d >> BSH;
            int r = atomicAdd(&cnt[b], 1);
            int slot = sofs[b] + r;
            int pos = base[b] + r;
            int lo = s | ((d & 511) << 17);
            recs[slot] = (long long)(unsigned)lo |
                         ((long long)__float_as_int(ew[e]) << 32);
            gdst[slot] = (pos < CAP) ? (b * CAP + pos) : -1;  // overflow guard
        }
    }
    __syncthreads();
    int nrec = min(EPB, NE - e0);
    for (int i = tid; i < nrec; i += 256) {
        int gd = gdst[i];
        if (gd >= 0) rec[gd] = recs[i];
    }
}

// ---------- phase B: per-bucket counting sort by (dst_local, src_slice) ----------
// dst-major slice-minor: node's edges contiguous; slice-ordered within node keeps
// the grid's gathers in ~2 adjacent ~2.1 MB table slices (XCD-L2 resident).
__global__ __launch_bounds__(256) void kB_sort(const int* __restrict__ gcur,
                                               const int2* __restrict__ rec,
                                               int2* __restrict__ evs,
                                               int* __restrict__ ofs,
                                               int* __restrict__ ocn) {
    __shared__ int hist[2048], lofs[2048], ssc[256];
    int tid = threadIdx.x, b = blockIdx.x;
    int nb0 = b << BSH;
    int nnodes = min(512, NN - nb0);
    int cntb = min(gcur[b], CAP);
    for (int i = tid; i < 2048; i += 256) hist[i] = 0;
    __syncthreads();
    const int2* rb = rec + (size_t)b * CAP;
    for (int i = tid; i < cntb; i += 256) {
        int rx = rb[i].x;
        int bin = (((rx >> 17) & 511) << 2) | ((rx & 0x1FFFF) >> 15);
        atomicAdd(&hist[bin], 1);
    }
    __syncthreads();
    int base = tid * 8, ls = 0, lh[8];
#pragma unroll
    for (int j = 0; j < 8; ++j) {
        lh[j] = hist[base + j];
        ls += lh[j];
    }
    ssc[tid] = ls;
    __syncthreads();
    for (int off = 1; off < 256; off <<= 1) {
        int v = (tid >= off) ? ssc[tid - off] : 0;
        __syncthreads();
        ssc[tid] += v;
        __syncthreads();
    }
    int ex = ssc[tid] - ls;
#pragma unroll
    for (int j = 0; j < 8; ++j) {
        lofs[base + j] = ex;
        ex += lh[j];
    }
    __syncthreads();
    for (int l = tid; l < nnodes; l += 256) {
        int c = hist[4 * l] + hist[4 * l + 1] + hist[4 * l + 2] + hist[4 * l + 3];
        ofs[nb0 + l] = b * CAP + lofs[4 * l];
        ocn[nb0 + l] = c;
    }
    __syncthreads();
    for (int i = tid; i < 2048; i += 256) hist[i] = 0;
    __syncthreads();
    int2* eb = evs + (size_t)b * CAP;
    for (int i = tid; i < cntb; i += 256) {
        int2 r = rb[i];
        int bin = (((r.x >> 17) & 511) << 2) | ((r.x & 0x1FFFF) >> 15);
        int rk = atomicAdd(&hist[bin], 1);
        eb[lofs[bin] + rk] = make_int2(r.x & 0x1FFFF, r.y);
    }
}

// ---------- prep: gcur zero + weight tables + x@W1p -> Hd, one dispatch ----------
__global__ __launch_bounds__(256) void k_prep(const float* __restrict__ x,
                                              const float* __restrict__ W1p,
                                              const float* __restrict__ W1m,
                                              const float* __restrict__ wih1,
                                              const float* __restrict__ whh1,
                                              const float* __restrict__ W2p,
                                              const float* __restrict__ W2m,
                                              const float* __restrict__ wih2,
                                              const float* __restrict__ whh2,
                                              half_t* __restrict__ Hd,
                                              half_t* __restrict__ W1sw,
                                              half_t* __restrict__ W2sw,
                                              half_t* __restrict__ W2pf,
                                              int* __restrict__ gcur) {
    __shared__ float sWp[FIN * H];   // proj weights
    __shared__ float sx[8][FIN];     // proj inputs
    __shared__ float P2l[32 * NC];   // weight blocks: P2 = W2p @ W2m
    int b = blockIdx.x, tid = threadIdx.x;
    if (b < NPROJ) {  // ---- h1 = x @ W1p (8 nodes/block) -> dense Hd ----
        for (int i = tid; i < FIN * H; i += 256) sWp[i] = W1p[i];
        int nb = b * 8;
        int nl = tid >> 5, j = tid & 31;
        int n = nb + nl;
        if (n < NN) sx[nl][j] = x[(size_t)n * FIN + j];
        __syncthreads();
        float acc = 0.f;
#pragma unroll
        for (int k = 0; k < FIN; ++k) acc += sx[nl][k] * sWp[k * H + j];
        if (n < NN) Hd[(size_t)n * 32 + j] = (half_t)acc;
        return;
    }
    int wb = b - NPROJ;
    if (wb == 0 && tid < NBK) gcur[tid] = 0;  // replaces hipMemsetAsync dispatch
    if (wb < 40) {  // ---- layer-1 table: 2 slabs x 10 ct ----
        int i = wb * 256 + tid;  // < 10240
        int j = i & 7, lane = (i >> 3) & 63;
        int rest = i >> 9;  // 0..19
        int ct = rest % NCT1, s = rest / NCT1;
        int k = s * 32 + (lane >> 4) * 8 + j;
        int col = ct * 16 + (lane & 15);
        int g = col >> 5, jj = col & 31;  // g: 0=r 1=z 2=i_n 3=h_n 4=identity
        float v = 0.f;
        if (g <= 2) {
            if (k < 32) {  // input side (agg): fold W1m @ wih1^T
                float acc = 0.f;
#pragma unroll
                for (int t = 0; t < H; ++t) acc += W1m[k * H + t] * wih1[(g * H + jj) * H + t];
                v = acc;
            } else if (g < 2) {  // r,z hidden side
                v = whh1[(g * H + jj) * H + (k - 32)];
            }                     // g==2 (i_n), k>=32 -> 0
        } else if (g == 3) {      // h_n: hidden side only
            if (k >= 32) v = whh1[(2 * H + jj) * H + (k - 32)];
        } else {                  // identity: pass h1 (k=32..63) to C cols 128..159
            if (k >= 32 && (k - 32) == jj) v = 1.f;
        }
        W1sw[i] = (half_t)v;
    } else if (wb < 112) {  // ---- layer-2 table: 3 slabs x 12 ct ----
        for (int e = tid; e < 32 * NC; e += 256) {  // P2[k][t] = sum_u W2p[k,u]*W2m[u,t]
            int k = e / NC, t = e % NC;
            float a = 0.f;
#pragma unroll
            for (int u = 0; u < NC; ++u) a += W2p[k * NC + u] * W2m[u * NC + t];
            P2l[e] = a;
        }
        __syncthreads();
        int i2 = (wb - 40) * 256 + tid;  // < 18432
        int j = i2 & 7, lane = (i2 >> 3) & 63;
        int rest = i2 >> 9;  // 0..35
        int ct = rest % NCT2, s = rest / NCT2;
        int k = s * 32 + (lane >> 4) * 8 + j;  // 0..95
        int col = ct * 16 + (lane & 15);       // 0..191
        int g = col / 48, jj = col % 48;       // g: 0=r 1=z 2=i_n 3=h_n
        float v = 0.f;
        if (jj < NC) {
            if (g <= 2) {
                if (k < 32) {  // input side (agg): P2 @ wih2^T
                    float acc = 0.f;
#pragma unroll
                    for (int t = 0; t < NC; ++t)
                        acc += P2l[k * NC + t] * wih2[(g * NC + jj) * NC + t];
                    v = acc;
                } else if (k < 72 && g < 2) {  // r,z hidden side
                    v = whh2[(g * NC + jj) * NC + (k - 32)];
                }
            } else {  // g==3 (h_n)
                if (k >= 32 && k < 72) v = whh2[(2 * NC + jj) * NC + (k - 32)];
            }
        }
        W2sw[i2] = (half_t)v;
    } else {  // ---- W2pf: W2p fragment-linear fp16, 1 slab x 3 ct ----
        int i3 = (wb - 112) * 256 + tid;  // < 1536
        int j = i3 & 7, lane = (i3 >> 3) & 63, ct = i3 >> 9;  // ct 0..2
        int k = (lane >> 4) * 8 + j;        // 0..31
        int col = ct * 16 + (lane & 15);    // 0..47
        W2pf[i3] = (half_t)((col < NC) ? W2p[k * NC + col] : 0.f);
    }
}

// ---------- L1 fused: split-run agg (2 groups/node) + MFMA GRU1 + relu ----------
// 128 threads / 16 nodes: 8 lanes/node = 2 x 4-lane groups, each half the edge
// run. 2x wave supply, halved serial length, same instr count. Wave 0 combines
// partials (fp32) + runs MFMA/epilogue; wave 1 exits after agg.
__global__ __launch_bounds__(128, 4) void k_l1(const int* __restrict__ ofs,
                                               const int* __restrict__ ocn,
                                               const int2* __restrict__ evs,
                                               const half_t* __restrict__ Hd,
                                               const half8* __restrict__ W1sw,
                                               const float* __restrict__ bih,
                                               const float* __restrict__ bhh,
                                               half_t* __restrict__ Hh) {
    __shared__ half8 aggT[16][9];  // 144B row stride: bank-uniform b128 access
    int tid = threadIdx.x;
    int n0 = blockIdx.x * 16;
    half8 a1;
    if (tid < 64) a1 = ((const half8*)Hd)[(size_t)(n0 + (tid & 15)) * 4 + (tid >> 4)];
    {  // agg: node nl, group g (half-run), col-quad q
        int nl = tid >> 3, s = tid & 7, g = s >> 2, q = s & 3;
        int n = n0 + nl;
        int s0 = ofs[n], c = ocn[n];
        int c0 = (c + 1) >> 1;
        int eb = g ? (s0 + c0) : s0;
        int ee = g ? (s0 + c) : (s0 + c0);
        float acc[8] = {0.f, 0.f, 0.f, 0.f, 0.f, 0.f, 0.f, 0.f};
        agg_run(eb, ee, q, evs, Hd, acc);
        half8 o;
#pragma unroll
        for (int t = 0; t < 8; ++t) o[t] = (half_t)acc[t];
        aggT[nl][s] = o;
    }
    __syncthreads();
    if (tid >= 64) return;  // wave 1 done
    int lane = tid, m16 = lane & 15, qq = lane >> 4;
    half8 pa = aggT[m16][qq], pb = aggT[m16][4 + qq];
    half8 a0;
#pragma unroll
    for (int t = 0; t < 8; ++t) a0[t] = (half_t)((float)pa[t] + (float)pb[t]);
    f32x4 macc[NCT1];
#pragma unroll
    for (int ct = 0; ct < NCT1; ++ct) macc[ct] = (f32x4){0.f, 0.f, 0.f, 0.f};
#pragma unroll
    for (int ct = 0; ct < NCT1; ++ct) {
        macc[ct] = __builtin_amdgcn_mfma_f32_16x16x32_f16(a0, W1sw[ct * 64 + lane], macc[ct], 0, 0, 0);
        macc[ct] = __builtin_amdgcn_mfma_f32_16x16x32_f16(a1, W1sw[(NCT1 + ct) * 64 + lane], macc[ct], 0, 0, 0);
    }
#pragma unroll
    for (int ct = 0; ct < 2; ++ct) {
        int j = ct * 16 + m16;
        float br = bih[j] + bhh[j];
        float bz = bih[H + j] + bhh[H + j];
        float bi = bih[2 * H + j], bh = bhh[2 * H + j];
#pragma unroll
        for (int m = 0; m < 4; ++m) {
            int node = n0 + qq * 4 + m;  // C/D: row = quad*4 + reg, col = lane&15
            float r = sigm_(macc[ct][m] + br);
            float z = sigm_(macc[2 + ct][m] + bz);
            float ng = tanh_(macc[4 + ct][m] + bi + r * (macc[6 + ct][m] + bh));
            float hj = macc[8 + ct][m];  // identity gate: h1[node][j]
            float o = fmaxf((1.f - z) * ng + z * hj, 0.f);
            Hh[(size_t)node * 32 + j] = (half_t)o;
        }
    }
}

// ---------- L2 fused: h2-via-MFMA + split-run agg + MFMA GRU2 + log_softmax ----------
__global__ __launch_bounds__(128, 4) void k_l2(const int* __restrict__ ofs,
                                               const int* __restrict__ ocn,
                                               const int2* __restrict__ evs,
                                               const half_t* __restrict__ Hh,
                                               const half8* __restrict__ W2sw,
                                               const half8* __restrict__ W2pf,
                                               const float* __restrict__ bih,
                                               const float* __restrict__ bhh,
                                               float* __restrict__ out) {
    __shared__ half8 aggT[16][9];   // 2304B, padded
    __shared__ half_t h2c[16][72];  // 2304B: h2 cols 0..39, zeros 40..71 (144B stride)
    int tid = threadIdx.x;
    int n0 = blockIdx.x * 16;
    if (tid < 64) {  // wave 0: h2 via MFMA (A = Hh rows of the block's 16 nodes)
        int lane = tid, m16 = lane & 15, qq = lane >> 4;
        half8 ah = ((const half8*)Hh)[(size_t)(n0 + m16) * 4 + qq];
        f32x4 hC[3];
#pragma unroll
        for (int ct = 0; ct < 3; ++ct) hC[ct] = (f32x4){0.f, 0.f, 0.f, 0.f};
#pragma unroll
        for (int ct = 0; ct < 3; ++ct)
            hC[ct] = __builtin_amdgcn_mfma_f32_16x16x32_f16(ah, W2pf[ct * 64 + lane], hC[ct], 0, 0, 0);
        // C-layout park (cols 40..47 are 0 from W2pf zero-pad)
#pragma unroll
        for (int ct = 0; ct < 3; ++ct)
#pragma unroll
            for (int m = 0; m < 4; ++m)
                h2c[qq * 4 + m][ct * 16 + m16] = (half_t)hC[ct][m];
    } else {  // wave 1: zero h2c cols 48..71
        int t2 = tid - 64;
        for (int i5 = t2; i5 < 16 * 24; i5 += 64)
            h2c[i5 / 24][48 + i5 % 24] = (half_t)0.f;
    }
    {  // agg (both waves): node nl, group g, col-quad q
        int nl = tid >> 3, s = tid & 7, g = s >> 2, q = s & 3;
        int n = n0 + nl;
        int s0 = ofs[n], c = ocn[n];
        int c0 = (c + 1) >> 1;
        int eb = g ? (s0 + c0) : s0;
        int ee = g ? (s0 + c) : (s0 + c0);
        float acc[8] = {0.f, 0.f, 0.f, 0.f, 0.f, 0.f, 0.f, 0.f};
        agg_run(eb, ee, q, evs, Hh, acc);
        half8 o;
#pragma unroll
        for (int t = 0; t < 8; ++t) o[t] = (half_t)acc[t];
        aggT[nl][s] = o;
    }
    __syncthreads();
    if (tid >= 64) return;  // wave 1 done
    int lane = tid, m16 = lane & 15, qq = lane >> 4;
    half8 pa = aggT[m16][qq], pb = aggT[m16][4 + qq];
    half8 a0;
#pragma unroll
    for (int t = 0; t < 8; ++t) a0[t] = (half_t)((float)pa[t] + (float)pb[t]);
    half8 a1 = *(const half8*)&h2c[m16][qq * 8];       // h2 cols 0..31
    half8 a2 = *(const half8*)&h2c[m16][32 + qq * 8];  // cols 32..63 (40+ = 0)
    f32x4 macc[NCT2];
#pragma unroll
    for (int ct = 0; ct < NCT2; ++ct) macc[ct] = (f32x4){0.f, 0.f, 0.f, 0.f};
#pragma unroll
    for (int ct = 0; ct < NCT2; ++ct) {
        macc[ct] = __builtin_amdgcn_mfma_f32_16x16x32_f16(a0, W2sw[ct * 64 + lane], macc[ct], 0, 0, 0);
        macc[ct] = __builtin_amdgcn_mfma_f32_16x16x32_f16(a1, W2sw[(NCT2 + ct) * 64 + lane], macc[ct], 0, 0, 0);
        macc[ct] = __builtin_amdgcn_mfma_f32_16x16x32_f16(a2, W2sw[(2 * NCT2 + ct) * 64 + lane], macc[ct], 0, 0, 0);
    }
    float v[3][4];
#pragma unroll
    for (int ct = 0; ct < 3; ++ct) {
        int j = ct * 16 + m16;
        int jc = (j < NC) ? j : (NC - 1);  // clamp (lanes with j>=40 produce unused values)
        float br = bih[jc] + bhh[jc];
        float bz = bih[NC + jc] + bhh[NC + jc];
        float bi = bih[2 * NC + jc], bh = bhh[2 * NC + jc];
#pragma unroll
        for (int m = 0; m < 4; ++m) {
            float r = sigm_(macc[ct][m] + br);
            float z = sigm_(macc[3 + ct][m] + bz);
            float ng = tanh_(macc[6 + ct][m] + bi + r * (macc[9 + ct][m] + bh));
            float hj = (float)h2c[qq * 4 + m][jc];
            v[ct][m] = (1.f - z) * ng + z * hj;
        }
    }
    bool v2ok = (m16 < 8);  // ct=2 covers j=32..39 only for m16<8
#pragma unroll
    for (int m = 0; m < 4; ++m) {
        float mx = fmaxf(v[0][m], v[1][m]);
        if (v2ok) mx = fmaxf(mx, v[2][m]);
#pragma unroll
        for (int d = 1; d < 16; d <<= 1) mx = fmaxf(mx, __shfl_xor(mx, d));
        float se = __expf(v[0][m] - mx) + __expf(v[1][m] - mx) +
                   (v2ok ? __expf(v[2][m] - mx) : 0.f);
#pragma unroll
        for (int d = 1; d < 16; d <<= 1) se += __shfl_xor(se, d);
        float ls = mx + __logf(se);
        int node = n0 + qq * 4 + m;
        out[(size_t)node * NC + m16] = v[0][m] - ls;
        out[(size_t)node * NC + 16 + m16] = v[1][m] - ls;
        if (v2ok) out[(size_t)node * NC + 32 + m16] = v[2][m] - ls;
    }
}

extern "C" void kernel_launch(void* const* d_in, const int* in_sizes, int n_in,
                              void* d_out, int out_size, void* d_ws, size_t ws_size,
                              hipStream_t stream) {
    const float* x = (const float*)d_in[0];
    const int* ei = (const int*)d_in[1];
    const float* ew = (const float*)d_in[2];
    const float* W1p = (const float*)d_in[3];
    const float* W1m = (const float*)d_in[4];
    const float* g1wih = (const float*)d_in[5];
    const float* g1whh = (const float*)d_in[6];
    const float* g1bih = (const float*)d_in[7];
    const float* g1bhh = (const float*)d_in[8];
    const float* W2p = (const float*)d_in[9];
    const float* W2m = (const float*)d_in[10];
    const float* g2wih = (const float*)d_in[11];
    const float* g2whh = (const float*)d_in[12];
    const float* g2bih = (const float*)d_in[13];
    const float* g2bhh = (const float*)d_in[14];
    float* ws = (float*)d_ws;

    // workspace layout (float indices), ~47.8 MB:
    //  rec  [0, 4264960)         kA bucket scratch
    //  evs  [4264960, 8529920)   sorted records
    //  Hd   [8529920, 10130176)  dense [NN][32] fp16 h1 table
    //  Hh   [10130176, 11730432) dense [NN][32] fp16 hrelu table
    //  ofs  [11730432, 11830432) int[NN]
    //  ocn  [11830432, 11930432) int[NN]
    //  gcur [11930432, 11930688)
    //  W1sw (10240 h) / W2sw (18432 h) / W2pf (1536 h) tail
    long long* rec = (long long*)ws;
    int2* evs = (int2*)(ws + 4264960);
    half_t* Hd = (half_t*)(ws + 8529920);
    half_t* Hh = (half_t*)(ws + 10130176);
    int* ofs = (int*)(ws + 11730432);
    int* ocn = (int*)(ws + 11830432);
    int* gcur = (int*)(ws + 11930432);
    half_t* W1sw = (half_t*)(ws + 11930688);
    half_t* W2sw = W1sw + 10240;
    half_t* W2pf = W2sw + 18432;
    float* out = (float*)d_out;

    // 5 dispatches total
    k_prep<<<NPROJ + NWB, 256, 0, stream>>>(x, W1p, W1m, g1wih, g1whh,
                                            W2p, W2m, g2wih, g2whh,
                                            Hd, W1sw, W2sw, W2pf, gcur);
    kA_bucket<<<(NE + EPB - 1) / EPB, 256, 0, stream>>>(ei, ew, gcur, rec);
    kB_sort<<<NBK, 256, 0, stream>>>(gcur, (const int2*)rec, evs, ofs, ocn);
    k_l1<<<NN / 16, 128, 0, stream>>>(ofs, ocn, evs, Hd, (const half8*)W1sw,
                                      g1bih, g1bhh, Hh);
    k_l2<<<NN / 16, 128, 0, stream>>>(ofs, ocn, evs, Hh, (const half8*)W2sw,
                                      (const half8*)W2pf, g2bih, g2bhh, out);
}